// Round 21
// baseline (120.011 us; speedup 1.0000x reference)
//
#include <hip/hip_runtime.h>
#include <hip/hip_bf16.h>
#include <math.h>

#define NR 4096
#define NS 768

// Outputs (flat, fp32): depth[4096] | image[4096*2] | wsum[4096] | weights[4096*768] | z_vals[4096*768]
#define OFF_IMAGE   (NR)
#define OFF_WSUM    (NR*3)
#define OFF_WEIGHTS (NR*4)
#define OFF_ZVALS   (NR*4 + NR*NS)

typedef short bf16x8 __attribute__((ext_vector_type(8)));
typedef float f32x4  __attribute__((ext_vector_type(4)));

static __device__ __forceinline__ unsigned cvt_pk_bf16(float a, float b){
    unsigned r;
    asm("v_cvt_pk_bf16_f32 %0, %1, %2" : "=v"(r) : "v"(a), "v"(b));
    return r;
}
static __device__ __forceinline__ f32x4 zero4(){ f32x4 r = {0.f,0.f,0.f,0.f}; return r; }
// zero-instruction compiler fence (r10/r11/r14/r17-proven safe)
static __device__ __forceinline__ void ldsfence(){ asm volatile("" ::: "memory"); }

// ---------------------------------------------------------------------------
// TWO-TILE ILP INTERLEAVE on the r17 base (112 us verified): each wave
// processes tile pairs (A,B) with independent 8 KB bounce halves; phases
// interleaved G1A,G1B | W1A,W1B | G2A,G2B | ... so chain B's MFMAs/packs
// fill chain A's LDS-drain stalls (and vice versa). All layout math, relu
// form (fmaxf), and fp32 rgb are byte-identical to the r17/r20-proven code —
// only duplicated with A/B suffixes. Condemned levers excluded: pk_relu
// (NaN x3), XOR swizzle (NaN x2), setprio (-perf).
// Bounce layout (r14-proven):
//   write (uint2): word = F*128 + (g>>1)*64 + c*4 + (g&1)*2
//   read  (b128) : word = F*128 + (g&1)*64 + c*4,  F-part rbase incl. (g>>1)
// LDS: 4 waves x 16 KB bounce + 16 KB stash = 80 KB -> 2 blocks/CU.
// ---------------------------------------------------------------------------
__global__ __launch_bounds__(256, 2) void mlp_mfma_kernel(
    const float* __restrict__ rays_o, const float* __restrict__ rays_d,
    const float* __restrict__ timev,
    const float* __restrict__ W1, const float* __restrict__ b1,
    const float* __restrict__ W2, const float* __restrict__ b2,
    const float* __restrict__ w_sig, const float* __restrict__ b_sig,
    const float* __restrict__ Wc1, const float* __restrict__ bc1,
    const float* __restrict__ Wc2, const float* __restrict__ bc2,
    float* __restrict__ alpha_out,   // [NR*NS] (aliases weights slot of d_out)
    float* __restrict__ rgb_out)     // [NR*NS][2] fp32 in d_ws
{
    __shared__ __align__(16) unsigned bounce[4][4096];     // 16 KB per wave (A|B)
    __shared__ __align__(16) unsigned stash[16*64*4];      // 16 frag slots
    const int wid  = threadIdx.x >> 6;
    const int lane = threadIdx.x & 63;
    const int g = lane >> 4;          // 0..3
    const int c = lane & 15;          // 0..15

    // ---- stash (block-shared, built by wave 0) — r17-exact ----
    if (wid == 0) {
        #pragma unroll
        for (int ft = 0; ft < 4; ++ft) {
            const int col = ft*16 + c;
            unsigned u0=0,u1=0,u2=0,u3=0, d0=0,d1=0;
            if (g == 0) {
                u0 = cvt_pk_bf16(W1[0*64+col], W1[1*64+col]);
                u1 = cvt_pk_bf16(W1[2*64+col], W1[3*64+col]);
                u2 = cvt_pk_bf16(b1[col], 0.f);
                d0 = cvt_pk_bf16(Wc1[0*64+col], Wc1[1*64+col]);
                d1 = cvt_pk_bf16(Wc1[2*64+col], bc1[col]);
            }
            unsigned* p = &stash[(ft*64 + lane)*4];
            p[0]=u0; p[1]=u1; p[2]=u2; p[3]=u3;
            unsigned* q = &stash[((4+ft)*64 + lane)*4];
            q[0]=d0; q[1]=d1; q[2]=0; q[3]=0;
        }
        #pragma unroll
        for (int kt = 0; kt < 2; ++kt) {
            unsigned s[4], w[4];
            #pragma unroll
            for (int p = 0; p < 4; ++p) {
                int k = kt*32 + 8*g + 2*p;
                s[p] = (c == 0) ? cvt_pk_bf16(w_sig[k], w_sig[k+1]) : 0u;
                w[p] = (c < 2)  ? cvt_pk_bf16(Wc2[k*2+c], Wc2[(k+1)*2+c]) : 0u;
            }
            unsigned* ps = &stash[((8+kt)*64 + lane)*4];
            ps[0]=s[0]; ps[1]=s[1]; ps[2]=s[2]; ps[3]=s[3];
            unsigned* pw = &stash[((10+kt)*64 + lane)*4];
            pw[0]=w[0]; pw[1]=w[1]; pw[2]=w[2]; pw[3]=w[3];
        }
        #pragma unroll
        for (int ft = 0; ft < 4; ++ft) {
            float* pb = reinterpret_cast<float*>(&stash[((12+ft)*64 + lane)*4]);
            #pragma unroll
            for (int r = 0; r < 4; ++r) pb[r] = b2[ft*16 + g*4 + r];
        }
    }

    // ---- hot A-frags in registers — r17-exact ----
    auto ldfrag = [&](const float* __restrict__ W, int k0, int col)->bf16x8 {
        union { bf16x8 v; unsigned u[4]; } r;
        #pragma unroll
        for (int p = 0; p < 4; ++p) {
            int k = k0 + 2*p;
            r.u[p] = cvt_pk_bf16(W[k*64 + col], W[(k+1)*64 + col]);
        }
        return r.v;
    };
    bf16x8 bW2A[2][4], bWc1A[2][4];
    #pragma unroll
    for (int ft = 0; ft < 4; ++ft) {
        const int col = ft*16 + c;
        #pragma unroll
        for (int kt = 0; kt < 2; ++kt) {
            bW2A[kt][ft]  = ldfrag(W2,         kt*32 + 8*g, col);
            bWc1A[kt][ft] = ldfrag(Wc1 + 3*64, kt*32 + 8*g, col);
        }
    }
    const float bsg = b_sig[0];
    f32x4 bc2v;
    bc2v[0] = (g==0) ? bc2[0] : 0.f;
    bc2v[1] = (g==0) ? bc2[1] : 0.f;
    bc2v[2] = 0.f; bc2v[3] = 0.f;

    __syncthreads();

    unsigned* BWA = &bounce[wid][0];
    unsigned* BWB = &bounce[wid][2048];
    // conflict-free bijection (r14-proven, no XOR):
    const int wbase = (g>>1)*64 + c*4 + (g&1)*2;         // write word base
    const int rbase = (g>>1)*128 + (g&1)*64 + c*4;       // read word base (incl. F-part)
    auto SL = [&](int s)->bf16x8 {
        return *reinterpret_cast<const bf16x8*>(&stash[(s*64 + lane)*4]);
    };
    auto RDp = [&](unsigned* BW, int kt, int nt)->bf16x8 {
        return *reinterpret_cast<const bf16x8*>(&BW[rbase + (nt*4 + kt*2)*128]);
    };
    auto WRp = [&](unsigned* BW, const f32x4& a, int F){
        unsigned pk0 = cvt_pk_bf16(fmaxf(a[0],0.f), fmaxf(a[1],0.f));
        unsigned pk1 = cvt_pk_bf16(fmaxf(a[2],0.f), fmaxf(a[3],0.f));
        *reinterpret_cast<uint2*>(&BW[wbase + F*128]) = make_uint2(pk0, pk1);
    };

    const int gwave = blockIdx.x*4 + wid;

    #pragma unroll 1
    for (int tp = 0; tp < 3; ++tp) {
        const int tileA = gwave*6 + tp*2;
        const int tileB = tileA + 1;

        // ---- per-tile scalars (A and B) ----
        const int nA = tileA / 12, nB = tileB / 12;
        const int sA = (tileA - nA*12)*64 + lane;
        const int sB = (tileB - nB*12)*64 + lane;
        const float zA = 0.01f + 0.8f * ((float)sA * (1.0f/767.0f));
        const float zB = 0.01f + 0.8f * ((float)sB * (1.0f/767.0f));
        const float oxA = rays_o[3*nA+0], oyA = rays_o[3*nA+1], ozA = rays_o[3*nA+2];
        const float dxA = rays_d[3*nA+0], dyA = rays_d[3*nA+1], dzA = rays_d[3*nA+2];
        const float tmA = timev[nA];
        const float oxB = rays_o[3*nB+0], oyB = rays_o[3*nB+1], ozB = rays_o[3*nB+2];
        const float dxB = rays_d[3*nB+0], dyB = rays_d[3*nB+1], dzB = rays_d[3*nB+2];
        const float tmB = timev[nB];

        const unsigned p01A = cvt_pk_bf16(
            fminf(fmaxf(fmaf(dxA, zA, oxA), -1.f), 1.f),
            fminf(fmaxf(fmaf(dyA, zA, oyA), -1.f), 1.f));
        const unsigned p23A = cvt_pk_bf16(
            fminf(fmaxf(fmaf(dzA, zA, ozA), -1.f), 1.f), tmA);
        const unsigned p01B = cvt_pk_bf16(
            fminf(fmaxf(fmaf(dxB, zB, oxB), -1.f), 1.f),
            fminf(fmaxf(fmaf(dyB, zB, oyB), -1.f), 1.f));
        const unsigned p23B = cvt_pk_bf16(
            fminf(fmaxf(fmaf(dzB, zB, ozB), -1.f), 1.f), tmB);

        f32x4 accA[4][4], accB[4][4];

        // ================ GEMM1 (A then B) ================
        {
            bf16x8 a1[4];
            #pragma unroll
            for (int ft = 0; ft < 4; ++ft) a1[ft] = SL(ft);
            #pragma unroll
            for (int nt = 0; nt < 4; ++nt) {
                unsigned q0 = (unsigned)__shfl((int)p01A, nt*16 + c);
                unsigned q1 = (unsigned)__shfl((int)p23A, nt*16 + c);
                union { bf16x8 v; unsigned u[4]; } b;
                b.u[0] = (g==0) ? q0 : 0u;
                b.u[1] = (g==0) ? q1 : 0u;
                b.u[2] = (g==0) ? 0x00003F80u : 0u;
                b.u[3] = 0u;
                #pragma unroll
                for (int ft = 0; ft < 4; ++ft)
                    accA[ft][nt] = __builtin_amdgcn_mfma_f32_16x16x32_bf16(
                        a1[ft], b.v, zero4(), 0, 0, 0);
            }
            #pragma unroll
            for (int nt = 0; nt < 4; ++nt) {
                unsigned q0 = (unsigned)__shfl((int)p01B, nt*16 + c);
                unsigned q1 = (unsigned)__shfl((int)p23B, nt*16 + c);
                union { bf16x8 v; unsigned u[4]; } b;
                b.u[0] = (g==0) ? q0 : 0u;
                b.u[1] = (g==0) ? q1 : 0u;
                b.u[2] = (g==0) ? 0x00003F80u : 0u;
                b.u[3] = 0u;
                #pragma unroll
                for (int ft = 0; ft < 4; ++ft)
                    accB[ft][nt] = __builtin_amdgcn_mfma_f32_16x16x32_bf16(
                        a1[ft], b.v, zero4(), 0, 0, 0);
            }
        }
        ldsfence();
        #pragma unroll
        for (int ft = 0; ft < 4; ++ft)
            #pragma unroll
            for (int nt = 0; nt < 4; ++nt) { WRp(BWA, accA[ft][nt], nt*4+ft); }
        #pragma unroll
        for (int ft = 0; ft < 4; ++ft)
            #pragma unroll
            for (int nt = 0; nt < 4; ++nt) { WRp(BWB, accB[ft][nt], nt*4+ft); }
        ldsfence();

        // ================ GEMM2 (A then B) ================
        {
            f32x4 b2v[4];
            #pragma unroll
            for (int ft = 0; ft < 4; ++ft)
                b2v[ft] = *reinterpret_cast<const f32x4*>(&stash[((12+ft)*64 + lane)*4]);
            #pragma unroll
            for (int nt = 0; nt < 4; ++nt) {
                bf16x8 f0 = RDp(BWA, 0, nt), f1 = RDp(BWA, 1, nt);
                #pragma unroll
                for (int ft = 0; ft < 4; ++ft) {
                    f32x4 d = __builtin_amdgcn_mfma_f32_16x16x32_bf16(bW2A[0][ft], f0, b2v[ft], 0,0,0);
                    accA[ft][nt] = __builtin_amdgcn_mfma_f32_16x16x32_bf16(bW2A[1][ft], f1, d, 0,0,0);
                }
            }
            #pragma unroll
            for (int nt = 0; nt < 4; ++nt) {
                bf16x8 f0 = RDp(BWB, 0, nt), f1 = RDp(BWB, 1, nt);
                #pragma unroll
                for (int ft = 0; ft < 4; ++ft) {
                    f32x4 d = __builtin_amdgcn_mfma_f32_16x16x32_bf16(bW2A[0][ft], f0, b2v[ft], 0,0,0);
                    accB[ft][nt] = __builtin_amdgcn_mfma_f32_16x16x32_bf16(bW2A[1][ft], f1, d, 0,0,0);
                }
            }
        }
        ldsfence();
        #pragma unroll
        for (int ft = 0; ft < 4; ++ft)
            #pragma unroll
            for (int nt = 0; nt < 4; ++nt) { WRp(BWA, accA[ft][nt], nt*4+ft); }
        #pragma unroll
        for (int ft = 0; ft < 4; ++ft)
            #pragma unroll
            for (int nt = 0; nt < 4; ++nt) { WRp(BWB, accB[ft][nt], nt*4+ft); }
        ldsfence();

        // ================ GEMM3 + sigma (A then B) ================
        f32x4 sigDA[4], sigDB[4];
        {
            bf16x8 ad[4];
            #pragma unroll
            for (int ft = 0; ft < 4; ++ft) ad[ft] = SL(4+ft);
            bf16x8 ws0 = SL(8), ws1 = SL(9);
            union { bf16x8 v; unsigned u[4]; } fdA, fdB;
            fdA.u[0] = (g==0) ? cvt_pk_bf16(dxA, dyA) : 0u;
            fdA.u[1] = (g==0) ? cvt_pk_bf16(dzA, 1.0f) : 0u;
            fdA.u[2] = 0u; fdA.u[3] = 0u;
            fdB.u[0] = (g==0) ? cvt_pk_bf16(dxB, dyB) : 0u;
            fdB.u[1] = (g==0) ? cvt_pk_bf16(dzB, 1.0f) : 0u;
            fdB.u[2] = 0u; fdB.u[3] = 0u;
            #pragma unroll
            for (int nt = 0; nt < 4; ++nt) {
                bf16x8 f0 = RDp(BWA, 0, nt), f1 = RDp(BWA, 1, nt);
                #pragma unroll
                for (int ft = 0; ft < 4; ++ft) {
                    f32x4 d = __builtin_amdgcn_mfma_f32_16x16x32_bf16(bWc1A[0][ft], f0, zero4(), 0,0,0);
                    d = __builtin_amdgcn_mfma_f32_16x16x32_bf16(bWc1A[1][ft], f1, d, 0,0,0);
                    accA[ft][nt] = __builtin_amdgcn_mfma_f32_16x16x32_bf16(ad[ft], fdA.v, d, 0,0,0);
                }
                f32x4 sd = __builtin_amdgcn_mfma_f32_16x16x32_bf16(ws0, f0, zero4(), 0,0,0);
                sigDA[nt] = __builtin_amdgcn_mfma_f32_16x16x32_bf16(ws1, f1, sd, 0,0,0);
            }
            #pragma unroll
            for (int nt = 0; nt < 4; ++nt) {
                bf16x8 f0 = RDp(BWB, 0, nt), f1 = RDp(BWB, 1, nt);
                #pragma unroll
                for (int ft = 0; ft < 4; ++ft) {
                    f32x4 d = __builtin_amdgcn_mfma_f32_16x16x32_bf16(bWc1A[0][ft], f0, zero4(), 0,0,0);
                    d = __builtin_amdgcn_mfma_f32_16x16x32_bf16(bWc1A[1][ft], f1, d, 0,0,0);
                    accB[ft][nt] = __builtin_amdgcn_mfma_f32_16x16x32_bf16(ad[ft], fdB.v, d, 0,0,0);
                }
                f32x4 sd = __builtin_amdgcn_mfma_f32_16x16x32_bf16(ws0, f0, zero4(), 0,0,0);
                sigDB[nt] = __builtin_amdgcn_mfma_f32_16x16x32_bf16(ws1, f1, sd, 0,0,0);
            }
        }
        ldsfence();
        #pragma unroll
        for (int ft = 0; ft < 4; ++ft)
            #pragma unroll
            for (int nt = 0; nt < 4; ++nt) { WRp(BWA, accA[ft][nt], nt*4+ft); }
        #pragma unroll
        for (int ft = 0; ft < 4; ++ft)
            #pragma unroll
            for (int nt = 0; nt < 4; ++nt) { WRp(BWB, accB[ft][nt], nt*4+ft); }
        ldsfence();

        // ---- sigma redistribute + alpha (A, then B) ----
        {
            float v0 = __shfl(sigDA[0][0], c);
            float v1 = __shfl(sigDA[1][0], c);
            float v2 = __shfl(sigDA[2][0], c);
            float v3 = __shfl(sigDA[3][0], c);
            float pre = (g==0) ? v0 : ((g==1) ? v1 : ((g==2) ? v2 : v3));
            pre += bsg;
            float sig = fmaxf(pre, 0.f) + __logf(1.f + __expf(-fabsf(pre)));
            float dl  = (sA == NS-1) ? (0.8f/768.0f) : (0.8f/767.0f);
            alpha_out[tileA*64 + lane] = 1.0f - __expf(-dl * sig);
        }
        {
            float v0 = __shfl(sigDB[0][0], c);
            float v1 = __shfl(sigDB[1][0], c);
            float v2 = __shfl(sigDB[2][0], c);
            float v3 = __shfl(sigDB[3][0], c);
            float pre = (g==0) ? v0 : ((g==1) ? v1 : ((g==2) ? v2 : v3));
            pre += bsg;
            float sig = fmaxf(pre, 0.f) + __logf(1.f + __expf(-fabsf(pre)));
            float dl  = (sB == NS-1) ? (0.8f/768.0f) : (0.8f/767.0f);
            alpha_out[tileB*64 + lane] = 1.0f - __expf(-dl * sig);
        }

        // ================ GEMM4 + rgb (A then B) ================
        {
            bf16x8 c20 = SL(10), c21 = SL(11);
            f32x4 rgbDA[4], rgbDB[4];
            #pragma unroll
            for (int nt = 0; nt < 4; ++nt) {
                bf16x8 f0 = RDp(BWA, 0, nt), f1 = RDp(BWA, 1, nt);
                f32x4 d = __builtin_amdgcn_mfma_f32_16x16x32_bf16(c20, f0, bc2v, 0,0,0);
                rgbDA[nt] = __builtin_amdgcn_mfma_f32_16x16x32_bf16(c21, f1, d, 0,0,0);
            }
            #pragma unroll
            for (int nt = 0; nt < 4; ++nt) {
                bf16x8 f0 = RDp(BWB, 0, nt), f1 = RDp(BWB, 1, nt);
                f32x4 d = __builtin_amdgcn_mfma_f32_16x16x32_bf16(c20, f0, bc2v, 0,0,0);
                rgbDB[nt] = __builtin_amdgcn_mfma_f32_16x16x32_bf16(c21, f1, d, 0,0,0);
            }
            ldsfence();
            {
                float a0 = __shfl(rgbDA[0][0], c), b0 = __shfl(rgbDA[0][1], c);
                float a1 = __shfl(rgbDA[1][0], c), b1v_ = __shfl(rgbDA[1][1], c);
                float a2 = __shfl(rgbDA[2][0], c), b2_ = __shfl(rgbDA[2][1], c);
                float a3 = __shfl(rgbDA[3][0], c), b3 = __shfl(rgbDA[3][1], c);
                float r0 = (g==0) ? a0 : ((g==1) ? a1 : ((g==2) ? a2 : a3));
                float r1 = (g==0) ? b0 : ((g==1) ? b1v_ : ((g==2) ? b2_ : b3));
                r0 = 1.0f / (1.0f + __expf(-r0));
                r1 = 1.0f / (1.0f + __expf(-r1));
                *reinterpret_cast<float2*>(&rgb_out[2*(tileA*64 + lane)]) = make_float2(r0, r1);
            }
            {
                float a0 = __shfl(rgbDB[0][0], c), b0 = __shfl(rgbDB[0][1], c);
                float a1 = __shfl(rgbDB[1][0], c), b1v_ = __shfl(rgbDB[1][1], c);
                float a2 = __shfl(rgbDB[2][0], c), b2_ = __shfl(rgbDB[2][1], c);
                float a3 = __shfl(rgbDB[3][0], c), b3 = __shfl(rgbDB[3][1], c);
                float r0 = (g==0) ? a0 : ((g==1) ? a1 : ((g==2) ? a2 : a3));
                float r1 = (g==0) ? b0 : ((g==1) ? b1v_ : ((g==2) ? b2_ : b3));
                r0 = 1.0f / (1.0f + __expf(-r0));
                r1 = 1.0f / (1.0f + __expf(-r1));
                *reinterpret_cast<float2*>(&rgb_out[2*(tileB*64 + lane)]) = make_float2(r0, r1);
            }
        }
    }
}

// ---------------------------------------------------------------------------
// Kernel 2: wave-per-ray compositing (proven correct since r1)
// ---------------------------------------------------------------------------
__global__ __launch_bounds__(256) void composite_kernel(
    const float* __restrict__ rgb,   // [NR][NS][2]
    float* __restrict__ out)
{
    int gtid = blockIdx.x * 256 + threadIdx.x;
    int ray  = gtid >> 6;
    int lane = threadIdx.x & 63;
    if (ray >= NR) return;

    float* __restrict__ depth_o = out;
    float* __restrict__ image_o = out + OFF_IMAGE;
    float* __restrict__ wsum_o  = out + OFF_WSUM;
    float* __restrict__ w_o     = out + OFF_WEIGHTS;   // alpha in, weights out
    float* __restrict__ z_o     = out + OFF_ZVALS;

    float T = 1.0f;
    float depth = 0.0f, wsum = 0.0f, im0 = 0.0f, im1 = 0.0f;

    for (int ch = 0; ch < NS/64; ++ch) {
        int s   = ch*64 + lane;
        int idx = ray*NS + s;
        float a  = w_o[idx];
        float zv = 0.01f + 0.8f * ((float)s * (1.0f/767.0f));
        float f  = 1.0f - a + 1e-15f;

        float p = f;
        #pragma unroll
        for (int off = 1; off < 64; off <<= 1) {
            float v = __shfl_up(p, off, 64);
            if (lane >= off) p *= v;
        }
        float excl = __shfl_up(p, 1, 64);
        if (lane == 0) excl = 1.0f;

        float wgt = a * T * excl;

        float r0 = rgb[2*idx + 0], r1 = rgb[2*idx + 1];
        depth = fmaf(wgt, zv, depth);
        wsum += wgt;
        im0   = fmaf(wgt, r0, im0);
        im1   = fmaf(wgt, r1, im1);

        w_o[idx] = wgt;
        z_o[idx] = zv;

        T *= __shfl(p, 63, 64);
    }

    #pragma unroll
    for (int off = 32; off >= 1; off >>= 1) {
        depth += __shfl_down(depth, off, 64);
        wsum  += __shfl_down(wsum , off, 64);
        im0   += __shfl_down(im0  , off, 64);
        im1   += __shfl_down(im1  , off, 64);
    }
    if (lane == 0) {
        depth_o[ray]      = depth;
        image_o[2*ray+0]  = im0;
        image_o[2*ray+1]  = im1;
        wsum_o[ray]       = wsum;
    }
}

extern "C" void kernel_launch(void* const* d_in, const int* in_sizes, int n_in,
                              void* d_out, int out_size, void* d_ws, size_t ws_size,
                              hipStream_t stream) {
    const float* rays_o = (const float*)d_in[0];
    const float* rays_d = (const float*)d_in[1];
    const float* timev  = (const float*)d_in[2];
    const float* W1     = (const float*)d_in[3];
    const float* b1     = (const float*)d_in[4];
    const float* W2     = (const float*)d_in[5];
    const float* b2     = (const float*)d_in[6];
    const float* w_sig  = (const float*)d_in[7];
    const float* b_sig  = (const float*)d_in[8];
    const float* Wc1    = (const float*)d_in[9];
    const float* bc1    = (const float*)d_in[10];
    const float* Wc2    = (const float*)d_in[11];
    const float* bc2    = (const float*)d_in[12];

    float* out   = (float*)d_out;
    float* alpha = out + OFF_WEIGHTS;      // stash alpha in the weights slot
    float* rgb   = (float*)d_ws;           // [NR][NS][2] fp32

    dim3 blk(256);
    // 2048 blocks * 4 waves * 3 pairs * 2 tiles * 64 samples = 4096*768
    hipLaunchKernelGGL(mlp_mfma_kernel, dim3(2048), blk, 0, stream,
                       rays_o, rays_d, timev, W1, b1, W2, b2, w_sig, b_sig,
                       Wc1, bc1, Wc2, bc2, alpha, rgb);

    hipLaunchKernelGGL(composite_kernel, dim3((NR*64)/256), blk, 0, stream, rgb, out);
}

// Round 22
// 112.140 us; speedup vs baseline: 1.0702x; 1.0702x over previous
//
#include <hip/hip_runtime.h>
#include <hip/hip_bf16.h>
#include <math.h>

#define NR 4096
#define NS 768

// Outputs (flat, fp32): depth[4096] | image[4096*2] | wsum[4096] | weights[4096*768] | z_vals[4096*768]
#define OFF_IMAGE   (NR)
#define OFF_WSUM    (NR*3)
#define OFF_WEIGHTS (NR*4)
#define OFF_ZVALS   (NR*4 + NR*NS)

typedef short bf16x8 __attribute__((ext_vector_type(8)));
typedef float f32x4  __attribute__((ext_vector_type(4)));

static __device__ __forceinline__ unsigned cvt_pk_bf16(float a, float b){
    unsigned r;
    asm("v_cvt_pk_bf16_f32 %0, %1, %2" : "=v"(r) : "v"(a), "v"(b));
    return r;
}
static __device__ __forceinline__ f32x4 zero4(){ f32x4 r = {0.f,0.f,0.f,0.f}; return r; }
// zero-instruction compiler fence (r10/r11/r14/r17/r20-proven safe)
static __device__ __forceinline__ void ldsfence(){ asm volatile("" ::: "memory"); }

// ---------------------------------------------------------------------------
// FINAL (r17/r20-exact, HW-verified 112 us twice): transposed full-tile MLP,
// all five matmuls (4->64, 64->64, 67->64, 64->1, 64->2) on the MFMA pipe,
// conflict-free bounce layout (no XOR), fmaxf relu, fp32 rgb.
// Session ledger: 745 (fp32 VALU) -> 193 (MFMA) -> 124 (spill fix + heads on
// MFMA) -> 112 (bank-conflict-free bounce). Closed levers: two-tile ILP (-8us,
// occupancy-fed latency hiding), slab restructure (-23us), setprio (-perf),
// launch-bounds hint (null), pk_relu (NaN x3), XOR swizzle (NaN x2).
// Bounce layout (r14-proven):
//   write (uint2): word = F*128 + (g>>1)*64 + c*4 + (g&1)*2
//   read  (b128) : word = F*128 + (g&1)*64 + c*4,  F-part rbase includes (g>>1)
// ---------------------------------------------------------------------------
__global__ __launch_bounds__(256, 3) void mlp_mfma_kernel(
    const float* __restrict__ rays_o, const float* __restrict__ rays_d,
    const float* __restrict__ timev,
    const float* __restrict__ W1, const float* __restrict__ b1,
    const float* __restrict__ W2, const float* __restrict__ b2,
    const float* __restrict__ w_sig, const float* __restrict__ b_sig,
    const float* __restrict__ Wc1, const float* __restrict__ bc1,
    const float* __restrict__ Wc2, const float* __restrict__ bc2,
    float* __restrict__ alpha_out,   // [NR*NS] (aliases weights slot of d_out)
    float* __restrict__ rgb_out)     // [NR*NS][2] fp32 in d_ws
{
    __shared__ __align__(16) unsigned bounce[4][2048];     // 8 KB per wave
    __shared__ __align__(16) unsigned stash[16*64*4];      // 16 frag slots
    const int wid  = threadIdx.x >> 6;
    const int lane = threadIdx.x & 63;
    const int g = lane >> 4;          // 0..3
    const int c = lane & 15;          // 0..15

    // ---- stash (block-shared, built by wave 0) ----
    if (wid == 0) {
        #pragma unroll
        for (int ft = 0; ft < 4; ++ft) {
            const int col = ft*16 + c;
            unsigned u0=0,u1=0,u2=0,u3=0, d0=0,d1=0;
            if (g == 0) {
                u0 = cvt_pk_bf16(W1[0*64+col], W1[1*64+col]);
                u1 = cvt_pk_bf16(W1[2*64+col], W1[3*64+col]);
                u2 = cvt_pk_bf16(b1[col], 0.f);
                d0 = cvt_pk_bf16(Wc1[0*64+col], Wc1[1*64+col]);
                d1 = cvt_pk_bf16(Wc1[2*64+col], bc1[col]);
            }
            unsigned* p = &stash[(ft*64 + lane)*4];
            p[0]=u0; p[1]=u1; p[2]=u2; p[3]=u3;
            unsigned* q = &stash[((4+ft)*64 + lane)*4];
            q[0]=d0; q[1]=d1; q[2]=0; q[3]=0;
        }
        #pragma unroll
        for (int kt = 0; kt < 2; ++kt) {
            unsigned s[4], w[4];
            #pragma unroll
            for (int p = 0; p < 4; ++p) {
                int k = kt*32 + 8*g + 2*p;
                s[p] = (c == 0) ? cvt_pk_bf16(w_sig[k], w_sig[k+1]) : 0u;
                w[p] = (c < 2)  ? cvt_pk_bf16(Wc2[k*2+c], Wc2[(k+1)*2+c]) : 0u;
            }
            unsigned* ps = &stash[((8+kt)*64 + lane)*4];
            ps[0]=s[0]; ps[1]=s[1]; ps[2]=s[2]; ps[3]=s[3];
            unsigned* pw = &stash[((10+kt)*64 + lane)*4];
            pw[0]=w[0]; pw[1]=w[1]; pw[2]=w[2]; pw[3]=w[3];
        }
        #pragma unroll
        for (int ft = 0; ft < 4; ++ft) {
            float* pb = reinterpret_cast<float*>(&stash[((12+ft)*64 + lane)*4]);
            #pragma unroll
            for (int r = 0; r < 4; ++r) pb[r] = b2[ft*16 + g*4 + r];
        }
    }

    // ---- hot A-frags in registers ----
    auto ldfrag = [&](const float* __restrict__ W, int k0, int col)->bf16x8 {
        union { bf16x8 v; unsigned u[4]; } r;
        #pragma unroll
        for (int p = 0; p < 4; ++p) {
            int k = k0 + 2*p;
            r.u[p] = cvt_pk_bf16(W[k*64 + col], W[(k+1)*64 + col]);
        }
        return r.v;
    };
    bf16x8 bW2A[2][4], bWc1A[2][4];
    #pragma unroll
    for (int ft = 0; ft < 4; ++ft) {
        const int col = ft*16 + c;
        #pragma unroll
        for (int kt = 0; kt < 2; ++kt) {
            bW2A[kt][ft]  = ldfrag(W2,         kt*32 + 8*g, col);
            bWc1A[kt][ft] = ldfrag(Wc1 + 3*64, kt*32 + 8*g, col);
        }
    }
    const float bsg = b_sig[0];
    f32x4 bc2v;
    bc2v[0] = (g==0) ? bc2[0] : 0.f;
    bc2v[1] = (g==0) ? bc2[1] : 0.f;
    bc2v[2] = 0.f; bc2v[3] = 0.f;

    __syncthreads();

    unsigned* BW = &bounce[wid][0];
    // conflict-free bijection (r14-proven, no XOR):
    const int wbase = (g>>1)*64 + c*4 + (g&1)*2;         // write word base
    const int rbase = (g>>1)*128 + (g&1)*64 + c*4;       // read word base (incl. F-part)
    auto SL = [&](int s)->bf16x8 {
        return *reinterpret_cast<const bf16x8*>(&stash[(s*64 + lane)*4]);
    };
    auto RD = [&](int kt, int nt)->bf16x8 {
        return *reinterpret_cast<const bf16x8*>(&BW[rbase + (nt*4 + kt*2)*128]);
    };

    const int gwave = blockIdx.x*4 + wid;

    #pragma unroll 1
    for (int tt = 0; tt < 6; ++tt) {
        const int tile = gwave*6 + tt;          // 0..49151
        const int n  = tile / 12;               // ray (wave-uniform)
        const int s0 = (tile - n*12) * 64;
        const int s  = s0 + lane;               // this lane's sample (step idx)

        const float z  = 0.01f + 0.8f * ((float)s * (1.0f/767.0f));
        const float ox = rays_o[3*n+0], oy = rays_o[3*n+1], oz = rays_o[3*n+2];
        const float dx = rays_d[3*n+0], dy = rays_d[3*n+1], dz = rays_d[3*n+2];
        const float tm = timev[n];

        const float px = fminf(fmaxf(fmaf(dx, z, ox), -1.f), 1.f);
        const float py = fminf(fmaxf(fmaf(dy, z, oy), -1.f), 1.f);
        const float pz = fminf(fmaxf(fmaf(dz, z, oz), -1.f), 1.f);
        const unsigned p01 = cvt_pk_bf16(px, py);
        const unsigned p23 = cvt_pk_bf16(pz, tm);

        f32x4 acc[4][4];

        // ---------------- GEMM1: W1ext^T @ X^T (K=32, bias at k=4) --------
        {
            bf16x8 a1[4];
            #pragma unroll
            for (int ft = 0; ft < 4; ++ft) a1[ft] = SL(ft);
            #pragma unroll
            for (int nt = 0; nt < 4; ++nt) {
                unsigned q0 = (unsigned)__shfl((int)p01, nt*16 + c);
                unsigned q1 = (unsigned)__shfl((int)p23, nt*16 + c);
                union { bf16x8 v; unsigned u[4]; } b;
                b.u[0] = (g==0) ? q0 : 0u;
                b.u[1] = (g==0) ? q1 : 0u;
                b.u[2] = (g==0) ? 0x00003F80u : 0u;   // bf16 1.0 at k=4
                b.u[3] = 0u;
                #pragma unroll
                for (int ft = 0; ft < 4; ++ft)
                    acc[ft][nt] = __builtin_amdgcn_mfma_f32_16x16x32_bf16(
                        a1[ft], b.v, zero4(), 0, 0, 0);
            }
        }
        // relu + bounce h1
        ldsfence();
        #pragma unroll
        for (int ft = 0; ft < 4; ++ft)
            #pragma unroll
            for (int nt = 0; nt < 4; ++nt) {
                unsigned pk0 = cvt_pk_bf16(fmaxf(acc[ft][nt][0],0.f), fmaxf(acc[ft][nt][1],0.f));
                unsigned pk1 = cvt_pk_bf16(fmaxf(acc[ft][nt][2],0.f), fmaxf(acc[ft][nt][3],0.f));
                *reinterpret_cast<uint2*>(&BW[wbase + (nt*4+ft)*128]) = make_uint2(pk0, pk1);
            }
        ldsfence();

        // ---------------- GEMM2: W2^T @ h1 (C-init = b2) -------------------
        {
            f32x4 b2v[4];
            #pragma unroll
            for (int ft = 0; ft < 4; ++ft)
                b2v[ft] = *reinterpret_cast<const f32x4*>(&stash[((12+ft)*64 + lane)*4]);
            #pragma unroll
            for (int nt = 0; nt < 4; ++nt) {
                bf16x8 f0 = RD(0, nt), f1 = RD(1, nt);
                #pragma unroll
                for (int ft = 0; ft < 4; ++ft) {
                    f32x4 d = __builtin_amdgcn_mfma_f32_16x16x32_bf16(bW2A[0][ft], f0, b2v[ft], 0,0,0);
                    acc[ft][nt] = __builtin_amdgcn_mfma_f32_16x16x32_bf16(bW2A[1][ft], f1, d, 0,0,0);
                }
            }
        }
        // relu + bounce h2
        ldsfence();
        #pragma unroll
        for (int ft = 0; ft < 4; ++ft)
            #pragma unroll
            for (int nt = 0; nt < 4; ++nt) {
                unsigned pk0 = cvt_pk_bf16(fmaxf(acc[ft][nt][0],0.f), fmaxf(acc[ft][nt][1],0.f));
                unsigned pk1 = cvt_pk_bf16(fmaxf(acc[ft][nt][2],0.f), fmaxf(acc[ft][nt][3],0.f));
                *reinterpret_cast<uint2*>(&BW[wbase + (nt*4+ft)*128]) = make_uint2(pk0, pk1);
            }
        ldsfence();

        // -------- GEMM3: Wc1^T @ [h2; dirs; 1] (3 k-steps) + sigma ---------
        f32x4 sigD[4];
        {
            bf16x8 ad[4];
            #pragma unroll
            for (int ft = 0; ft < 4; ++ft) ad[ft] = SL(4+ft);
            bf16x8 ws0 = SL(8), ws1 = SL(9);
            union { bf16x8 v; unsigned u[4]; } fd;
            fd.u[0] = (g==0) ? cvt_pk_bf16(dx, dy) : 0u;
            fd.u[1] = (g==0) ? cvt_pk_bf16(dz, 1.0f) : 0u;
            fd.u[2] = 0u; fd.u[3] = 0u;
            #pragma unroll
            for (int nt = 0; nt < 4; ++nt) {
                bf16x8 f0 = RD(0, nt), f1 = RD(1, nt);
                #pragma unroll
                for (int ft = 0; ft < 4; ++ft) {
                    f32x4 d = __builtin_amdgcn_mfma_f32_16x16x32_bf16(bWc1A[0][ft], f0, zero4(), 0,0,0);
                    d = __builtin_amdgcn_mfma_f32_16x16x32_bf16(bWc1A[1][ft], f1, d, 0,0,0);
                    acc[ft][nt] = __builtin_amdgcn_mfma_f32_16x16x32_bf16(ad[ft], fd.v, d, 0,0,0);
                }
                f32x4 sd = __builtin_amdgcn_mfma_f32_16x16x32_bf16(ws0, f0, zero4(), 0,0,0);
                sigD[nt] = __builtin_amdgcn_mfma_f32_16x16x32_bf16(ws1, f1, sd, 0,0,0);
            }
        }
        // relu + bounce cfeat
        ldsfence();
        #pragma unroll
        for (int ft = 0; ft < 4; ++ft)
            #pragma unroll
            for (int nt = 0; nt < 4; ++nt) {
                unsigned pk0 = cvt_pk_bf16(fmaxf(acc[ft][nt][0],0.f), fmaxf(acc[ft][nt][1],0.f));
                unsigned pk1 = cvt_pk_bf16(fmaxf(acc[ft][nt][2],0.f), fmaxf(acc[ft][nt][3],0.f));
                *reinterpret_cast<uint2*>(&BW[wbase + (nt*4+ft)*128]) = make_uint2(pk0, pk1);
            }
        ldsfence();

        // sigma redistribute (row 0 lives in lanes g==0, reg 0) + alpha
        {
            float v0 = __shfl(sigD[0][0], c);
            float v1 = __shfl(sigD[1][0], c);
            float v2 = __shfl(sigD[2][0], c);
            float v3 = __shfl(sigD[3][0], c);
            float pre = (g==0) ? v0 : ((g==1) ? v1 : ((g==2) ? v2 : v3));
            pre += bsg;
            float sig = fmaxf(pre, 0.f) + __logf(1.f + __expf(-fabsf(pre)));
            float dl  = (s == NS-1) ? (0.8f/768.0f) : (0.8f/767.0f);
            alpha_out[tile*64 + lane] = 1.0f - __expf(-dl * sig);
        }

        // ---------------- GEMM4: Wc2^T @ cfeat (rows 0,1) ------------------
        {
            bf16x8 c20 = SL(10), c21 = SL(11);
            f32x4 rgbD[4];
            #pragma unroll
            for (int nt = 0; nt < 4; ++nt) {
                bf16x8 f0 = RD(0, nt), f1 = RD(1, nt);
                f32x4 d = __builtin_amdgcn_mfma_f32_16x16x32_bf16(c20, f0, bc2v, 0,0,0);
                rgbD[nt] = __builtin_amdgcn_mfma_f32_16x16x32_bf16(c21, f1, d, 0,0,0);
            }
            ldsfence();
            float a0 = __shfl(rgbD[0][0], c), b0 = __shfl(rgbD[0][1], c);
            float a1 = __shfl(rgbD[1][0], c), b1v_ = __shfl(rgbD[1][1], c);
            float a2 = __shfl(rgbD[2][0], c), b2_ = __shfl(rgbD[2][1], c);
            float a3 = __shfl(rgbD[3][0], c), b3 = __shfl(rgbD[3][1], c);
            float r0 = (g==0) ? a0 : ((g==1) ? a1 : ((g==2) ? a2 : a3));
            float r1 = (g==0) ? b0 : ((g==1) ? b1v_ : ((g==2) ? b2_ : b3));
            r0 = 1.0f / (1.0f + __expf(-r0));
            r1 = 1.0f / (1.0f + __expf(-r1));
            *reinterpret_cast<float2*>(&rgb_out[2*(tile*64 + lane)]) = make_float2(r0, r1);
        }
    }
}

// ---------------------------------------------------------------------------
// Kernel 2: wave-per-ray compositing (proven correct since r1)
// ---------------------------------------------------------------------------
__global__ __launch_bounds__(256) void composite_kernel(
    const float* __restrict__ rgb,   // [NR][NS][2]
    float* __restrict__ out)
{
    int gtid = blockIdx.x * 256 + threadIdx.x;
    int ray  = gtid >> 6;
    int lane = threadIdx.x & 63;
    if (ray >= NR) return;

    float* __restrict__ depth_o = out;
    float* __restrict__ image_o = out + OFF_IMAGE;
    float* __restrict__ wsum_o  = out + OFF_WSUM;
    float* __restrict__ w_o     = out + OFF_WEIGHTS;   // alpha in, weights out
    float* __restrict__ z_o     = out + OFF_ZVALS;

    float T = 1.0f;
    float depth = 0.0f, wsum = 0.0f, im0 = 0.0f, im1 = 0.0f;

    for (int ch = 0; ch < NS/64; ++ch) {
        int s   = ch*64 + lane;
        int idx = ray*NS + s;
        float a  = w_o[idx];
        float zv = 0.01f + 0.8f * ((float)s * (1.0f/767.0f));
        float f  = 1.0f - a + 1e-15f;

        float p = f;
        #pragma unroll
        for (int off = 1; off < 64; off <<= 1) {
            float v = __shfl_up(p, off, 64);
            if (lane >= off) p *= v;
        }
        float excl = __shfl_up(p, 1, 64);
        if (lane == 0) excl = 1.0f;

        float wgt = a * T * excl;

        float r0 = rgb[2*idx + 0], r1 = rgb[2*idx + 1];
        depth = fmaf(wgt, zv, depth);
        wsum += wgt;
        im0   = fmaf(wgt, r0, im0);
        im1   = fmaf(wgt, r1, im1);

        w_o[idx] = wgt;
        z_o[idx] = zv;

        T *= __shfl(p, 63, 64);
    }

    #pragma unroll
    for (int off = 32; off >= 1; off >>= 1) {
        depth += __shfl_down(depth, off, 64);
        wsum  += __shfl_down(wsum , off, 64);
        im0   += __shfl_down(im0  , off, 64);
        im1   += __shfl_down(im1  , off, 64);
    }
    if (lane == 0) {
        depth_o[ray]      = depth;
        image_o[2*ray+0]  = im0;
        image_o[2*ray+1]  = im1;
        wsum_o[ray]       = wsum;
    }
}

extern "C" void kernel_launch(void* const* d_in, const int* in_sizes, int n_in,
                              void* d_out, int out_size, void* d_ws, size_t ws_size,
                              hipStream_t stream) {
    const float* rays_o = (const float*)d_in[0];
    const float* rays_d = (const float*)d_in[1];
    const float* timev  = (const float*)d_in[2];
    const float* W1     = (const float*)d_in[3];
    const float* b1     = (const float*)d_in[4];
    const float* W2     = (const float*)d_in[5];
    const float* b2     = (const float*)d_in[6];
    const float* w_sig  = (const float*)d_in[7];
    const float* b_sig  = (const float*)d_in[8];
    const float* Wc1    = (const float*)d_in[9];
    const float* bc1    = (const float*)d_in[10];
    const float* Wc2    = (const float*)d_in[11];
    const float* bc2    = (const float*)d_in[12];

    float* out   = (float*)d_out;
    float* alpha = out + OFF_WEIGHTS;      // stash alpha in the weights slot
    float* rgb   = (float*)d_ws;           // [NR][NS][2] fp32

    dim3 blk(256);
    // 2048 blocks * 4 waves * 6 tiles * 64 samples = 4096*768 samples
    hipLaunchKernelGGL(mlp_mfma_kernel, dim3(2048), blk, 0, stream,
                       rays_o, rays_d, timev, W1, b1, W2, b2, w_sig, b_sig,
                       Wc1, bc1, Wc2, bc2, alpha, rgb);

    hipLaunchKernelGGL(composite_kernel, dim3((NR*64)/256), blk, 0, stream, rgb, out);
}